// Round 1
// baseline (34273.801 us; speedup 1.0000x reference)
//
#include <hip/hip_runtime.h>

static constexpr int B_ = 8;
static constexpr int C_ = 64;
static constexpr int H_ = 256;
static constexpr int W_ = 512;
static constexpr int K_ = 9;
static constexpr int PAD_ = 4;

// One scan step: buf[row irow] += relu(conv1d(buf[row iprev]) + bias).
// Generic strides so the same kernel serves UD/DU (conv along W, contiguous),
// LR/RL on a transposed buffer (conv along H, contiguous), or a strided
// fallback if workspace is too small.
// Block: 256 threads = 4 waves. Wave w handles c_out [blockIdx.y*16 + w*4 .. +3]
// for 64 consecutive columns. Each thread: 4 c_out x 1 column.
__global__ __launch_bounds__(256) void scan_step_kernel(
    float* __restrict__ buf, const float* __restrict__ w,
    const float* __restrict__ bias, const int ncols, const int irow,
    const int iprev, const long long rowStride, const long long colStride,
    const long long chanStride)
{
    __shared__ float s_in[C_][72];   // 64 ci x (64 cols + 8 halo), zero-padded

    const int t = threadIdx.x;
    const int tx = t & 63;
    const int waveId = t >> 6;
    const int tile0 = blockIdx.x * 64;
    const long long base = (long long)blockIdx.z * C_ * chanStride;
    // wave-uniform c_out base -> weight/bias loads become scalar (s_load)
    const int co = __builtin_amdgcn_readfirstlane(blockIdx.y * 16 + waveId * 4);

    // Stage carry row (iprev) into LDS with halo of PAD_ on each side.
    for (int idx = t; idx < C_ * 72; idx += 256) {
        const int ci = idx / 72;
        const int cc = idx - ci * 72;
        const int g = tile0 + cc - PAD_;
        float v = 0.0f;
        if (g >= 0 && g < ncols)
            v = buf[base + ci * chanStride + iprev * rowStride +
                    (long long)g * colStride];
        s_in[ci][cc] = v;
    }
    __syncthreads();

    float a0 = 0.f, a1 = 0.f, a2 = 0.f, a3 = 0.f;
    const float* wp0 = w + (long long)co * (C_ * K_);
    for (int ci = 0; ci < C_; ++ci) {
        const float* wp = wp0 + ci * K_;
        float w0[K_], w1[K_], w2[K_], w3[K_];
#pragma unroll
        for (int k = 0; k < K_; ++k) {
            w0[k] = wp[k];
            w1[k] = wp[1 * C_ * K_ + k];
            w2[k] = wp[2 * C_ * K_ + k];
            w3[k] = wp[3 * C_ * K_ + k];
        }
#pragma unroll
        for (int k = 0; k < K_; ++k) {
            const float iv = s_in[ci][tx + k];
            a0 = fmaf(w0[k], iv, a0);
            a1 = fmaf(w1[k], iv, a1);
            a2 = fmaf(w2[k], iv, a2);
            a3 = fmaf(w3[k], iv, a3);
        }
    }

    const int col = tile0 + tx;
    const long long rowOff =
        base + (long long)irow * rowStride + (long long)col * colStride;
    const float b0 = bias[co + 0], b1 = bias[co + 1];
    const float b2 = bias[co + 2], b3 = bias[co + 3];
    {
        const long long o = rowOff + (long long)(co + 0) * chanStride;
        const float v = a0 + b0;
        buf[o] += (v > 0.f ? v : 0.f);
    }
    {
        const long long o = rowOff + (long long)(co + 1) * chanStride;
        const float v = a1 + b1;
        buf[o] += (v > 0.f ? v : 0.f);
    }
    {
        const long long o = rowOff + (long long)(co + 2) * chanStride;
        const float v = a2 + b2;
        buf[o] += (v > 0.f ? v : 0.f);
    }
    {
        const long long o = rowOff + (long long)(co + 3) * chanStride;
        const float v = a3 + b3;
        buf[o] += (v > 0.f ? v : 0.f);
    }
}

// out[b,c,s,r] = in[b,c,r,s] for each of the B*C planes.
__global__ __launch_bounds__(256) void transpose_kernel(
    const float* __restrict__ in, float* __restrict__ out,
    const int R, const int S)
{
    __shared__ float tile[32][33];
    const size_t plane = (size_t)blockIdx.z * R * S;
    const int s0 = blockIdx.x * 32;
    const int r0 = blockIdx.y * 32;
    const int tx = threadIdx.x;
    const int ty = threadIdx.y;
#pragma unroll
    for (int j = 0; j < 32; j += 8)
        tile[ty + j][tx] = in[plane + (size_t)(r0 + ty + j) * S + s0 + tx];
    __syncthreads();
#pragma unroll
    for (int j = 0; j < 32; j += 8)
        out[plane + (size_t)(s0 + ty + j) * R + r0 + tx] = tile[tx][ty + j];
}

extern "C" void kernel_launch(void* const* d_in, const int* in_sizes, int n_in,
                              void* d_out, int out_size, void* d_ws,
                              size_t ws_size, hipStream_t stream)
{
    const float* x    = (const float*)d_in[0];
    const float* w_ud = (const float*)d_in[1];
    const float* b_ud = (const float*)d_in[2];
    const float* w_du = (const float*)d_in[3];
    const float* b_du = (const float*)d_in[4];
    const float* w_lr = (const float*)d_in[5];
    const float* b_lr = (const float*)d_in[6];
    const float* w_rl = (const float*)d_in[7];
    const float* b_rl = (const float*)d_in[8];
    float* out = (float*)d_out;
    float* ws  = (float*)d_ws;

    const size_t total = (size_t)B_ * C_ * H_ * W_;
    hipMemcpyAsync(out, x, total * sizeof(float), hipMemcpyDeviceToDevice,
                   stream);

    const long long chan = (long long)H_ * W_;  // 131072 elements per channel

    // --- up->down then down->up: conv along W, rows indexed by h ---
    {
        dim3 g(W_ / 64, 4, B_);
        for (int i = 1; i < H_; ++i)
            scan_step_kernel<<<g, 256, 0, stream>>>(
                out, w_ud, b_ud, W_, i, i - 1, (long long)W_, 1LL, chan);
        for (int i = H_ - 2; i >= 0; --i)
            scan_step_kernel<<<g, 256, 0, stream>>>(
                out, w_du, b_du, W_, i, i + 1, (long long)W_, 1LL, chan);
    }

    const bool useT = ws_size >= total * sizeof(float);
    if (useT) {
        // transpose [b,c,h,w] -> [b,c,w,h] so LR/RL convs are contiguous
        {
            dim3 gt(W_ / 32, H_ / 32, B_ * C_);
            transpose_kernel<<<gt, dim3(32, 8), 0, stream>>>(out, ws, H_, W_);
        }
        dim3 g(H_ / 64, 4, B_);
        for (int i = 1; i < W_; ++i)
            scan_step_kernel<<<g, 256, 0, stream>>>(
                ws, w_lr, b_lr, H_, i, i - 1, (long long)H_, 1LL, chan);
        for (int i = W_ - 2; i >= 0; --i)
            scan_step_kernel<<<g, 256, 0, stream>>>(
                ws, w_rl, b_rl, H_, i, i + 1, (long long)H_, 1LL, chan);
        {
            dim3 gt(H_ / 32, W_ / 32, B_ * C_);
            transpose_kernel<<<gt, dim3(32, 8), 0, stream>>>(ws, out, W_, H_);
        }
    } else {
        // fallback: strided (uncoalesced) scans directly on out
        dim3 g(H_ / 64, 4, B_);
        for (int i = 1; i < W_; ++i)
            scan_step_kernel<<<g, 256, 0, stream>>>(
                out, w_lr, b_lr, H_, i, i - 1, 1LL, (long long)W_, chan);
        for (int i = W_ - 2; i >= 0; --i)
            scan_step_kernel<<<g, 256, 0, stream>>>(
                out, w_rl, b_rl, H_, i, i + 1, 1LL, (long long)W_, chan);
    }
}